// Round 7
// baseline (209.851 us; speedup 1.0000x reference)
//
#include <hip/hip_runtime.h>

// STDP delta_w on MI355X, bf16-MFMA formulation (2-dispatch).
//   term1: dW1[o,p] = sum_k O[k,o]*TP[k,p], K = T*B = 1024  -> bf16 MFMA GEMM
//   term2: -coef[o]*W[o,p], coef[o] = sum_k O[k,o]*PO[k,o]  -> fp32 epilogue
//
// R7: coalesced GEMM epilogue — acc transposed through per-wave LDS slab
//     (union with K-loop tiles), W/C accessed as float4 in 256-B row runs.
// K-loop: BK=64, 3-bit XOR swizzle (0 conflicts, verified R6).
// Converter: verbatim R4 (at its 144 MB roofline, ~25 us).
//
// ws: AT bf16 [4096][1024] (8MB) | BT bf16 [4096][1024] (8MB) | coef f32[4096]

#define T_STEPS 64
#define B_SZ    16
#define PRE     4096
#define POST    4096
#define K_TOT   1024

typedef __attribute__((ext_vector_type(8))) unsigned short ushort8;
typedef __attribute__((ext_vector_type(8))) __bf16 bf16x8;
typedef __attribute__((ext_vector_type(4))) float floatx4;

__device__ __forceinline__ unsigned short f2bf(float f) {
    unsigned int u = __float_as_uint(f);
    u += 0x7fff + ((u >> 16) & 1);          // round-to-nearest-even
    return (unsigned short)(u >> 16);
}

__device__ __forceinline__ void glds16(const void* g, void* l) {
    __builtin_amdgcn_global_load_lds((const __attribute__((address_space(1))) void*)g,
                                     (__attribute__((address_space(3))) void*)l,
                                     16, 0, 0);
}

// ---------------------------------------------------------------------------
// Converter: grid = 256 blocks (matrix = blk>>7, p-chunk = blk&127), 256 thr.
// (verbatim R4 — passed 3x, at memory roofline)
__global__ __launch_bounds__(256) void trace_convert(
        const float* __restrict__ in_spikes,
        const float* __restrict__ out_spikes,
        unsigned short* __restrict__ AT,
        unsigned short* __restrict__ BT,
        float* __restrict__ coef) {
    __shared__ float ldsf[4096];             // [8 t][16 b][32 p] fp32, 16 KB
    __shared__ unsigned short ot[128 * 34];  // [128 k][32 p + 2 pad], 8.5 KB
    __shared__ float cbuf[8][33];
    const int tid  = threadIdx.x;
    const int wave = tid >> 6;
    const int lane = tid & 63;
    const bool isA = blockIdx.x >= 128;
    const int p0 = (blockIdx.x & 127) * 32;
    const float* src = isA ? out_spikes : in_spikes;
    unsigned short* dst = isA ? AT : BT;

    const int bA = tid >> 5;                 // chains (bA, p) and (bA+8, p)
    const int pA = tid & 31;

    float st0 = 0.f, st1 = 0.f, c0 = 0.f, c1 = 0.f;

    for (int tc = 0; tc < 8; ++tc) {
        const int T0 = tc * 8;
        #pragma unroll
        for (int i = 0; i < 4; ++i) {
            const int q  = (wave * 4 + i) * 64 + lane;  // float-quad id 0..1023
            const int p  = (q & 7) * 4;
            const int b  = (q >> 3) & 15;
            const int tl = q >> 7;
            const float* g = src + ((size_t)((T0 + tl) * 16 + b)) * 4096 + p0 + p;
            glds16(g, (char*)ldsf + (size_t)(wave * 4 + i) * 1024);
        }
        __syncthreads();

        #pragma unroll
        for (int tl = 0; tl < 8; ++tl) {
            const float x0 = ldsf[tl * 512 + bA * 32 + pA];
            const float x1 = ldsf[tl * 512 + (bA + 8) * 32 + pA];
            if (isA) {
                st0 = 0.5f * st0 + x0; c0 += x0 * st0;   // po update, then o*po
                st1 = 0.5f * st1 + x1; c1 += x1 * st1;
                ot[(tl * 16 + bA)     * 34 + pA] = f2bf(x0);
                ot[(tl * 16 + bA + 8) * 34 + pA] = f2bf(x1);
            } else {
                st0 = fminf(fmaxf(0.5f * st0 + x0, 0.f), 1.f);
                st1 = fminf(fmaxf(0.5f * st1 + x1, 0.f), 1.f);
                ot[(tl * 16 + bA)     * 34 + pA] = f2bf(st0);
                ot[(tl * 16 + bA + 8) * 34 + pA] = f2bf(st1);
            }
        }
        __syncthreads();

        const int pf = tid >> 3;             // 0..31
        const int c8 = tid & 7;
        #pragma unroll
        for (int i = 0; i < 2; ++i) {
            const int ch = c8 + i * 8;       // 16-B chunk 0..15
            ushort8 v;
            #pragma unroll
            for (int s = 0; s < 8; ++s) v[s] = ot[(ch * 8 + s) * 34 + pf];
            *(ushort8*)&dst[(size_t)(p0 + pf) * K_TOT + T0 * 16 + ch * 8] = v;
        }
    }

    if (isA) {
        cbuf[bA][pA] = c0 + c1;
        __syncthreads();
        if (tid < 32) {
            float s = 0.f;
            #pragma unroll
            for (int r = 0; r < 8; ++r) s += cbuf[r][tid];
            coef[p0 + tid] = s;
        }
    }
}

// ---------------------------------------------------------------------------
// bf16 MFMA GEMM: 128x128 tile, BK=64, 4 waves, 4x4 16x16x32 tiles x 2 halves,
// glds width-16 staging, 3-bit XOR swizzle; LDS-transposed float4 epilogue.
#define BK 64

__global__ __launch_bounds__(256) void stdp_gemm_mfma(
        const unsigned short* __restrict__ AT,   // [POST][K] bf16 bits
        const unsigned short* __restrict__ BT,   // [PRE][K]  bf16 bits
        const float* __restrict__ W,             // [POST][PRE]
        const float* __restrict__ coef,          // [POST]
        float* __restrict__ Cout) {              // [POST][PRE]
    __shared__ union {
        struct { unsigned short A[128 * BK]; unsigned short B[128 * BK]; } kl; // 32 KB
        float ep[4][16 * 68];                    // per-wave 16 rows x 68 (pad), 17.4 KB
    } sm;
    const int tid  = threadIdx.x;
    const int lane = tid & 63;
    const int wave = tid >> 6;
    const int quad = lane >> 4;
    const int wm = (wave >> 1) * 64;
    const int wn = (wave & 1) * 64;
    const int m0 = blockIdx.y * 128;
    const int n0 = blockIdx.x * 128;

    floatx4 acc[4][4];
    #pragma unroll
    for (int i = 0; i < 4; ++i)
        #pragma unroll
        for (int j = 0; j < 4; ++j)
            acc[i][j] = (floatx4){0.f, 0.f, 0.f, 0.f};

    // Staging: thread tid -> row srow = tid>>3 (+32 per instr), LDS slot tid&7,
    // which receives global chunk (tid&7) ^ (srow&7).
    const int srow = tid >> 3;                   // 0..31
    const int qg   = (tid & 7) ^ (srow & 7);
    const unsigned short* ga = &AT[(size_t)(m0 + srow) * K_TOT + qg * 8];
    const unsigned short* gb = &BT[(size_t)(n0 + srow) * K_TOT + qg * 8];
    char* laB = (char*)sm.kl.A + wave * 1024;    // wave-uniform base
    char* lbB = (char*)sm.kl.B + wave * 1024;

    const int rm = lane & 15;                    // fragment row (m or n)
    const int sw = rm & 7;                       // read-side swizzle

    for (int k0 = 0; k0 < K_TOT; k0 += BK) {
        #pragma unroll
        for (int i = 0; i < 4; ++i) {            // rows i*32 .. i*32+31
            glds16(ga + (size_t)i * 32 * K_TOT, laB + i * 4096);
            glds16(gb + (size_t)i * 32 * K_TOT, lbB + i * 4096);
        }
        ga += BK; gb += BK;
        __syncthreads();

        #pragma unroll
        for (int h = 0; h < 2; ++h) {            // two 32-k halves
            const int ks = ((h * 4 + quad) ^ sw) * 8;
            bf16x8 af[4], bv[4];
            #pragma unroll
            for (int i = 0; i < 4; ++i) {
                af[i] = *(const bf16x8*)&sm.kl.A[(wm + i * 16 + rm) * BK + ks];
                bv[i] = *(const bf16x8*)&sm.kl.B[(wn + i * 16 + rm) * BK + ks];
            }
            #pragma unroll
            for (int mi = 0; mi < 4; ++mi)
                #pragma unroll
                for (int ni = 0; ni < 4; ++ni)
                    acc[mi][ni] = __builtin_amdgcn_mfma_f32_16x16x32_bf16(
                        af[mi], bv[ni], acc[mi][ni], 0, 0, 0);
        }
        __syncthreads();
    }

    // Epilogue: C = acc - coef[o]*W via per-wave LDS transpose, float4 I/O.
    // MFMA C/D layout: col = rm, row = quad*4 + r (within each 16x16 tile).
    float* eb = sm.ep[wave];
    #pragma unroll
    for (int mi = 0; mi < 4; ++mi) {
        // scatter this 16-row x 64-col stripe into LDS (2-way banks = free)
        #pragma unroll
        for (int ni = 0; ni < 4; ++ni)
            #pragma unroll
            for (int r = 0; r < 4; ++r)
                eb[(quad * 4 + r) * 68 + ni * 16 + rm] = acc[mi][ni][r];
        __syncthreads();
        // gather: row = pass*4 + quad, 16 lanes x float4 = 256-B runs per row
        #pragma unroll
        for (int pass = 0; pass < 4; ++pass) {
            const int rloc = pass * 4 + quad;
            const int o = m0 + wm + mi * 16 + rloc;
            const float cf = coef[o];
            const int p = n0 + wn + rm * 4;
            const float4 a4 = *(const float4*)&eb[rloc * 68 + rm * 4];
            const float4 w4 = *(const float4*)&W[(size_t)o * PRE + p];
            float4 r4;
            r4.x = a4.x - cf * w4.x;
            r4.y = a4.y - cf * w4.y;
            r4.z = a4.z - cf * w4.z;
            r4.w = a4.w - cf * w4.w;
            *(float4*)&Cout[(size_t)o * PRE + p] = r4;
        }
        __syncthreads();
    }
}

// ---------------------------------------------------------------------------
extern "C" void kernel_launch(void* const* d_in, const int* in_sizes, int n_in,
                              void* d_out, int out_size, void* d_ws, size_t ws_size,
                              hipStream_t stream) {
    const float* in_spikes  = (const float*)d_in[0];
    const float* out_spikes = (const float*)d_in[1];
    const float* weight     = (const float*)d_in[2];
    float* out = (float*)d_out;

    unsigned short* AT = (unsigned short*)d_ws;                 // 8 MB
    unsigned short* BT = AT + (size_t)POST * K_TOT;             // 8 MB
    float* coef = (float*)(BT + (size_t)PRE * K_TOT);           // 16 KB

    trace_convert<<<256, 256, 0, stream>>>(in_spikes, out_spikes, AT, BT, coef);

    dim3 grid(PRE / 128, POST / 128);
    stdp_gemm_mfma<<<grid, 256, 0, stream>>>(AT, BT, weight, coef, out);
}